// Round 11
// baseline (90.856 us; speedup 1.0000x reference)
//
#include <hip/hip_runtime.h>

// Problem constants (x: [128, 65536] fp32, LEVEL=8)
static constexpr int BROWS = 128;   // batch rows
static constexpr int T     = 65536; // samples per row
static constexpr int CL    = 256;   // chunk length = 2^LEVEL
static constexpr int NCH   = 256;   // chunks per row = T / CL (positions per node)
static constexpr int NODES = 256;   // 2^LEVEL leaves
static constexpr int KG    = 16;    // chunks handled per block (2048 blocks, 8/CU)
static constexpr int NGRP  = NCH / KG; // 16 chunk-groups per row
static constexpr int LSTR  = 257;   // padded LDS row stride (breaks bank conflicts)

// R11: single dispatch via last-block-per-row handoff, ATOMICS ONLY (no fences).
//  - partials published with atomicExch (native global_atomic_swap, performed at
//    the device coherence point; no -munsafe-fp-atomics dependency)
//  - __syncthreads drains vmcnt -> row ticket atomicAdd happens-after exchanges
//  - 16th arriver re-reads the row's 16x512 partials with AGENT-scope atomic
//    loads (L1-bypass) and finalizes entropy/keep in-dispatch.
// R1's 190-µs failure was 262K per-thread __threadfence L2-writebacks; this has
// zero fences and no block ever waits (no deadlock, dispatch-order-independent).

// Output row for Hadamard-order index h (in-place FWHT leaves Hadamard order):
//   c_nat[n] = H[bitrev8(n)], freq perm out[m] = c_nat[gray^-1(m)] => m = gray(bitrev8(h))
__device__ __forceinline__ int freq_pos(int h) {
    unsigned r = __brev((unsigned)h) >> 24; // bitrev8
    return (int)(r ^ (r >> 1));             // gray code
}

__device__ __forceinline__ void bfly01(float4& v) {
    // FWHT stages on j-bits 0,1 (within the float4)
    float4 w;
    w.x = v.x + v.y; w.y = v.x - v.y;
    w.z = v.z + v.w; w.w = v.z - v.w;
    v.x = w.x + w.z; v.z = w.x - w.z;
    v.y = w.y + w.w; v.w = w.y - w.w;
}

// Lane-exchange via DPP (VALU pipe — no LDS traffic). HW-validated.
// xor1 = quad_perm [1,0,3,2] = 0xB1; xor2 = quad_perm [2,3,0,1] = 0x4E;
// xor8 = row_ror:8 = 0x128 ((i+8)%16 == i^8 within a 16-lane row).
template<int CTRL>
__device__ __forceinline__ float xchg_dpp(float v) {
    return __builtin_bit_cast(float,
        __builtin_amdgcn_update_dpp(0, __builtin_bit_cast(int, v), CTRL, 0xF, 0xF, true));
}

template<int CTRL>
__device__ __forceinline__ void stage_dpp(float4& v1, float4& v2, float sgn) {
    float o;
    o = xchg_dpp<CTRL>(v1.x); v1.x = fmaf(sgn, v1.x, o);
    o = xchg_dpp<CTRL>(v1.y); v1.y = fmaf(sgn, v1.y, o);
    o = xchg_dpp<CTRL>(v1.z); v1.z = fmaf(sgn, v1.z, o);
    o = xchg_dpp<CTRL>(v1.w); v1.w = fmaf(sgn, v1.w, o);
    o = xchg_dpp<CTRL>(v2.x); v2.x = fmaf(sgn, v2.x, o);
    o = xchg_dpp<CTRL>(v2.y); v2.y = fmaf(sgn, v2.y, o);
    o = xchg_dpp<CTRL>(v2.z); v2.z = fmaf(sgn, v2.z, o);
    o = xchg_dpp<CTRL>(v2.w); v2.w = fmaf(sgn, v2.w, o);
}

__device__ __forceinline__ void stage_shfl(float4& v1, float4& v2, float sgn, int mask) {
    float o;
    o = __shfl_xor(v1.x, mask, 64); v1.x = fmaf(sgn, v1.x, o);
    o = __shfl_xor(v1.y, mask, 64); v1.y = fmaf(sgn, v1.y, o);
    o = __shfl_xor(v1.z, mask, 64); v1.z = fmaf(sgn, v1.z, o);
    o = __shfl_xor(v1.w, mask, 64); v1.w = fmaf(sgn, v1.w, o);
    o = __shfl_xor(v2.x, mask, 64); v2.x = fmaf(sgn, v2.x, o);
    o = __shfl_xor(v2.y, mask, 64); v2.y = fmaf(sgn, v2.y, o);
    o = __shfl_xor(v2.z, mask, 64); v2.z = fmaf(sgn, v2.z, o);
    o = __shfl_xor(v2.w, mask, 64); v2.w = fmaf(sgn, v2.w, o);
}

// Per block: 16 chunks of one batch row -> 256-pt FWHT (dual-chunk wave layout)
// -> freq-ordered transposed coeffs write + per-node entropy partials published
// via atomicExch -> row ticket; the 16th arriver finalizes the row in-dispatch.
__global__ __launch_bounds__(256) void wht_fused(const float* __restrict__ x,
                                                 float* __restrict__ coeffs,
                                                 float* __restrict__ part,
                                                 int* __restrict__ cnt,
                                                 float* __restrict__ entropy,
                                                 float* __restrict__ keep) {
    __shared__ float lds[KG][LSTR]; // 16.5 KB; reused as 4x2x256 partial buffer later
    __shared__ int s_last;

    const int b    = blockIdx.x >> 4;  // 16 chunk-groups per row
    const int kg   = blockIdx.x & 15;
    const int k0   = kg * KG;
    const int lane = threadIdx.x & 63;
    const int wave = threadIdx.x >> 6; // 4 waves
    const int half = lane >> 5;        // which of 2 concurrent chunks
    const int L    = lane & 31;        // position within chunk (j-bits 2..6)

    const float* xb = x + (size_t)b * T;

    // lane owns the SAME 8 nodes (h = 4L+i and 128+4L+i) in every chunk
    int npos1[4], npos2[4];
    #pragma unroll
    for (int i = 0; i < 4; ++i) {
        npos1[i] = freq_pos(4 * L + i);
        npos2[i] = freq_pos(128 + 4 * L + i);
    }
    float A1[4] = {0.f,0.f,0.f,0.f}, B1[4] = {0.f,0.f,0.f,0.f};
    float A2[4] = {0.f,0.f,0.f,0.f}, B2[4] = {0.f,0.f,0.f,0.f};

    // Butterfly signs for the 5 cross-lane stages (loop-invariant)
    const float sgn0 = 1.0f - 2.0f * (float)((L >> 0) & 1);
    const float sgn1 = 1.0f - 2.0f * (float)((L >> 1) & 1);
    const float sgn2 = 1.0f - 2.0f * (float)((L >> 2) & 1);
    const float sgn3 = 1.0f - 2.0f * (float)((L >> 3) & 1);
    const float sgn4 = 1.0f - 2.0f * (float)((L >> 4) & 1);

    // Each wave handles 4 chunks as 2 iterations x 2 chunks (one per lane-half)
    #pragma unroll
    for (int it = 0; it < 2; ++it) {
        const int kl = wave * 4 + it * 2 + half; // local chunk row in LDS (0..15)
        const float* cp = xb + (size_t)(k0 + kl) * CL + 4 * L;
        float4 v1 = *(const float4*)(cp);        // j = 4L+i      (bit7=0)
        float4 v2 = *(const float4*)(cp + 128);  // j = 128+4L+i  (bit7=1)

        // FWHT stage j-bit7 (across the two registers, pure VALU)
        float4 t;
        t.x = v1.x - v2.x; t.y = v1.y - v2.y; t.z = v1.z - v2.z; t.w = v1.w - v2.w;
        v1.x += v2.x; v1.y += v2.y; v1.z += v2.z; v1.w += v2.w;
        v2 = t;

        // FWHT stages j-bits 0,1 (intra-float4)
        bfly01(v1);
        bfly01(v2);

        // FWHT stages j-bits 2..6 = lane xor 1,2,4,8,16.
        stage_dpp<0xB1>(v1, v2, sgn0);   // xor 1  (quad_perm [1,0,3,2])
        stage_dpp<0x4E>(v1, v2, sgn1);   // xor 2  (quad_perm [2,3,0,1])
        stage_shfl(v1, v2, sgn2, 4);     // xor 4  (ds_swizzle)
        stage_dpp<0x128>(v1, v2, sgn3);  // xor 8  (row_ror:8)
        stage_shfl(v1, v2, sgn4, 16);    // xor 16 (ds_swizzle)

        // scale by (1/sqrt2)^8 = 1/16; accumulate entropy partials; LDS scatter
        float c1[4] = {v1.x*0.0625f, v1.y*0.0625f, v1.z*0.0625f, v1.w*0.0625f};
        float c2[4] = {v2.x*0.0625f, v2.y*0.0625f, v2.z*0.0625f, v2.w*0.0625f};
        #pragma unroll
        for (int i = 0; i < 4; ++i) {
            const float s1 = c1[i] * c1[i];
            A1[i] += s1;
            B1[i] += s1 * __logf(s1 + 1e-35f); // c=0 -> term 0, matches p*log(p+eps)
            lds[kl][npos1[i]] = c1[i];
            const float s2 = c2[i] * c2[i];
            A2[i] += s2;
            B2[i] += s2 * __logf(s2 + 1e-35f);
            lds[kl][npos2[i]] = c2[i];
        }
    }
    __syncthreads();

    // Transposed, coalesced write: coeffs[b][m][k0 + kk .. kk+3]
    float* ob = coeffs + (size_t)b * T + k0;
    const int kk = (threadIdx.x & 3) * 4; // k offset within group (0,4,8,12)
    const int m0 = threadIdx.x >> 2;      // 0..63
    #pragma unroll
    for (int p = 0; p < 4; ++p) {
        const int m = p * 64 + m0;
        float4 v;
        v.x = lds[kk + 0][m];
        v.y = lds[kk + 1][m];
        v.z = lds[kk + 2][m];
        v.w = lds[kk + 3][m];
        *(float4*)(ob + (size_t)m * NCH + kk) = v;
    }
    __syncthreads();

    // Merge the two lane-halves (same node sets), then cross-wave reduce via LDS
    #pragma unroll
    for (int i = 0; i < 4; ++i) {
        A1[i] += __shfl_xor(A1[i], 32, 64); B1[i] += __shfl_xor(B1[i], 32, 64);
        A2[i] += __shfl_xor(A2[i], 32, 64); B2[i] += __shfl_xor(B2[i], 32, 64);
    }
    float* pl = &lds[0][0]; // need 4*512 = 2048 floats, have 16*257 = 4112
    if (half == 0) {
        #pragma unroll
        for (int i = 0; i < 4; ++i) {
            pl[wave * 512 + npos1[i]]       = A1[i];
            pl[wave * 512 + 256 + npos1[i]] = B1[i];
            pl[wave * 512 + npos2[i]]       = A2[i];
            pl[wave * 512 + 256 + npos2[i]] = B2[i];
        }
    }
    __syncthreads();

    {
        // Publish this block's 512 partials at the DEVICE coherence point.
        // atomicExch = global_atomic_swap: native, device-scope, no fp-atomic
        // flag dependency; counted by vmcnt so the next barrier drains it.
        const int n = threadIdx.x; // 0..255 = node
        const float A = pl[n] + pl[512 + n] + pl[1024 + n] + pl[1536 + n];
        const float B = pl[256 + n] + pl[768 + n] + pl[1280 + n] + pl[1792 + n];
        float* pp = part + (size_t)blockIdx.x * 512;
        atomicExch(pp + n,       A);
        atomicExch(pp + 256 + n, B);
    }
    __syncthreads(); // drains vmcnt -> all 512 exchanges performed at L2-device

    if (threadIdx.x == 0)
        s_last = (atomicAdd(&cnt[b], 1) == NGRP - 1) ? 1 : 0; // 16th arrival
    __syncthreads();
    if (!s_last) return;

    // ---- finalize row b (exactly one block per row; no waiting happened) ----
    // AGENT-scope atomic loads bypass L1 and read the device-coherent values.
    const int nn = threadIdx.x; // 0..255 = node
    float Af = 0.f, Bf = 0.f;
    const float* pb = part + (size_t)b * NGRP * 512;
    #pragma unroll
    for (int g = 0; g < NGRP; ++g) {
        Af += __hip_atomic_load(pb + g * 512 + nn,       __ATOMIC_RELAXED, __HIP_MEMORY_SCOPE_AGENT);
        Bf += __hip_atomic_load(pb + g * 512 + 256 + nn, __ATOMIC_RELAXED, __HIP_MEMORY_SCOPE_AGENT);
    }
    const float S = Af + 1e-8f;
    const float e = (Af * __logf(S) - Bf) / S;
    const bool kp = e > 0.1f;

    entropy[b * NODES + nn] = e;
    keep[b * NODES + nn]    = kp ? 1.0f : 0.0f;

    // Rare path (never fires for Gaussian input: e ≈ 4.7 >> 0.1). Caveat: zeros
    // race other XCDs' coeff lines in principle; same caveat as all accepted
    // prior versions' rare path.
    if (!kp) {
        float4 z = make_float4(0.f, 0.f, 0.f, 0.f);
        float4* cp = (float4*)(coeffs + ((size_t)b * NODES + nn) * NCH);
        for (int j = 0; j < NCH / 4; ++j) cp[j] = z;
    }
}

extern "C" void kernel_launch(void* const* d_in, const int* in_sizes, int n_in,
                              void* d_out, int out_size, void* d_ws, size_t ws_size,
                              hipStream_t stream) {
    const float* x = (const float*)d_in[0];

    float* coeffs  = (float*)d_out;                         // [128][256][256]
    float* entropy = coeffs + (size_t)BROWS * NODES * NCH;  // [128][256]
    float* keepf   = entropy + (size_t)BROWS * NODES;       // [128][256] as 0/1 float

    float* part = (float*)d_ws;                             // [2048][2][256] = 4 MB
    int*   cnt  = (int*)((char*)d_ws + (size_t)2048 * 512 * sizeof(float)); // [128]

    // ws is poisoned between iterations -> row tickets must be zeroed each
    // launch. Stream-ordered memset captures as a graph memset node (~0 µs, R1).
    // part needs no init: atomicExch overwrites unconditionally.
    hipMemsetAsync(cnt, 0, BROWS * sizeof(int), stream);

    wht_fused<<<dim3(BROWS * NGRP), dim3(256), 0, stream>>>(
        x, coeffs, part, cnt, entropy, keepf);
}

// Round 13
// 87.567 us; speedup vs baseline: 1.0376x; 1.0376x over previous
//
#include <hip/hip_runtime.h>

// Problem constants (x: [128, 65536] fp32, LEVEL=8)
static constexpr int BROWS = 128;   // batch rows
static constexpr int T     = 65536; // samples per row
static constexpr int CL    = 256;   // chunk length = 2^LEVEL
static constexpr int NCH   = 256;   // chunks per row = T / CL (positions per node)
static constexpr int NODES = 256;   // 2^LEVEL leaves
static constexpr int KG    = 16;    // chunks handled per block (2048 blocks, 8/CU)
static constexpr int NGRP  = NCH / KG; // 16 chunk-groups per row
static constexpr int LSTR  = 257;   // padded LDS row stride (breaks bank conflicts)

// MEASUREMENT ROUND (R4-style, resubmitted after R12 infra failure): exact R7
// two-kernel pipeline, but finalize is launched THREE times (idempotent).
// (dur - 84.05)/2 = finalize marginal cost.
// Fork: ~3 µs/launch -> the 28.5 µs is transition-attached -> ROOFLINE next.
//       ~25 µs/launch -> internally slow -> attack the read path next.

// Output row for Hadamard-order index h (in-place FWHT leaves Hadamard order):
//   c_nat[n] = H[bitrev8(n)], freq perm out[m] = c_nat[gray^-1(m)] => m = gray(bitrev8(h))
__device__ __forceinline__ int freq_pos(int h) {
    unsigned r = __brev((unsigned)h) >> 24; // bitrev8
    return (int)(r ^ (r >> 1));             // gray code
}

__device__ __forceinline__ void bfly01(float4& v) {
    // FWHT stages on j-bits 0,1 (within the float4)
    float4 w;
    w.x = v.x + v.y; w.y = v.x - v.y;
    w.z = v.z + v.w; w.w = v.z - v.w;
    v.x = w.x + w.z; v.z = w.x - w.z;
    v.y = w.y + w.w; v.w = w.y - w.w;
}

// Lane-exchange via DPP (VALU pipe — no LDS traffic). HW-validated.
// xor1 = quad_perm [1,0,3,2] = 0xB1; xor2 = quad_perm [2,3,0,1] = 0x4E;
// xor8 = row_ror:8 = 0x128 ((i+8)%16 == i^8 within a 16-lane row).
template<int CTRL>
__device__ __forceinline__ float xchg_dpp(float v) {
    return __builtin_bit_cast(float,
        __builtin_amdgcn_update_dpp(0, __builtin_bit_cast(int, v), CTRL, 0xF, 0xF, true));
}

template<int CTRL>
__device__ __forceinline__ void stage_dpp(float4& v1, float4& v2, float sgn) {
    float o;
    o = xchg_dpp<CTRL>(v1.x); v1.x = fmaf(sgn, v1.x, o);
    o = xchg_dpp<CTRL>(v1.y); v1.y = fmaf(sgn, v1.y, o);
    o = xchg_dpp<CTRL>(v1.z); v1.z = fmaf(sgn, v1.z, o);
    o = xchg_dpp<CTRL>(v1.w); v1.w = fmaf(sgn, v1.w, o);
    o = xchg_dpp<CTRL>(v2.x); v2.x = fmaf(sgn, v2.x, o);
    o = xchg_dpp<CTRL>(v2.y); v2.y = fmaf(sgn, v2.y, o);
    o = xchg_dpp<CTRL>(v2.z); v2.z = fmaf(sgn, v2.z, o);
    o = xchg_dpp<CTRL>(v2.w); v2.w = fmaf(sgn, v2.w, o);
}

__device__ __forceinline__ void stage_shfl(float4& v1, float4& v2, float sgn, int mask) {
    float o;
    o = __shfl_xor(v1.x, mask, 64); v1.x = fmaf(sgn, v1.x, o);
    o = __shfl_xor(v1.y, mask, 64); v1.y = fmaf(sgn, v1.y, o);
    o = __shfl_xor(v1.z, mask, 64); v1.z = fmaf(sgn, v1.z, o);
    o = __shfl_xor(v1.w, mask, 64); v1.w = fmaf(sgn, v1.w, o);
    o = __shfl_xor(v2.x, mask, 64); v2.x = fmaf(sgn, v2.x, o);
    o = __shfl_xor(v2.y, mask, 64); v2.y = fmaf(sgn, v2.y, o);
    o = __shfl_xor(v2.z, mask, 64); v2.z = fmaf(sgn, v2.z, o);
    o = __shfl_xor(v2.w, mask, 64); v2.w = fmaf(sgn, v2.w, o);
}

// Per block: 16 chunks of one batch row -> 256-pt FWHT (dual-chunk wave layout)
// -> freq-ordered transposed coeffs write + per-node entropy partials into ws.
// BYTE-IDENTICAL to the R2/R7 kernel (13.5 µs marginal, measured R4-R2).
__global__ __launch_bounds__(256) void wht_kernel(const float* __restrict__ x,
                                                  float* __restrict__ coeffs,
                                                  float* __restrict__ part) {
    __shared__ float lds[KG][LSTR]; // 16.5 KB; reused as 4x2x256 partial buffer later

    const int b    = blockIdx.x >> 4;  // 16 chunk-groups per row
    const int kg   = blockIdx.x & 15;
    const int k0   = kg * KG;
    const int lane = threadIdx.x & 63;
    const int wave = threadIdx.x >> 6; // 4 waves
    const int half = lane >> 5;        // which of 2 concurrent chunks
    const int L    = lane & 31;        // position within chunk (j-bits 2..6)

    const float* xb = x + (size_t)b * T;

    // lane owns the SAME 8 nodes (h = 4L+i and 128+4L+i) in every chunk
    int npos1[4], npos2[4];
    #pragma unroll
    for (int i = 0; i < 4; ++i) {
        npos1[i] = freq_pos(4 * L + i);
        npos2[i] = freq_pos(128 + 4 * L + i);
    }
    float A1[4] = {0.f,0.f,0.f,0.f}, B1[4] = {0.f,0.f,0.f,0.f};
    float A2[4] = {0.f,0.f,0.f,0.f}, B2[4] = {0.f,0.f,0.f,0.f};

    // Butterfly signs for the 5 cross-lane stages (loop-invariant)
    const float sgn0 = 1.0f - 2.0f * (float)((L >> 0) & 1);
    const float sgn1 = 1.0f - 2.0f * (float)((L >> 1) & 1);
    const float sgn2 = 1.0f - 2.0f * (float)((L >> 2) & 1);
    const float sgn3 = 1.0f - 2.0f * (float)((L >> 3) & 1);
    const float sgn4 = 1.0f - 2.0f * (float)((L >> 4) & 1);

    // Each wave handles 4 chunks as 2 iterations x 2 chunks (one per lane-half)
    #pragma unroll
    for (int it = 0; it < 2; ++it) {
        const int kl = wave * 4 + it * 2 + half; // local chunk row in LDS (0..15)
        const float* cp = xb + (size_t)(k0 + kl) * CL + 4 * L;
        float4 v1 = *(const float4*)(cp);        // j = 4L+i      (bit7=0)
        float4 v2 = *(const float4*)(cp + 128);  // j = 128+4L+i  (bit7=1)

        // FWHT stage j-bit7 (across the two registers, pure VALU)
        float4 t;
        t.x = v1.x - v2.x; t.y = v1.y - v2.y; t.z = v1.z - v2.z; t.w = v1.w - v2.w;
        v1.x += v2.x; v1.y += v2.y; v1.z += v2.z; v1.w += v2.w;
        v2 = t;

        // FWHT stages j-bits 0,1 (intra-float4)
        bfly01(v1);
        bfly01(v2);

        // FWHT stages j-bits 2..6 = lane xor 1,2,4,8,16.
        stage_dpp<0xB1>(v1, v2, sgn0);   // xor 1  (quad_perm [1,0,3,2])
        stage_dpp<0x4E>(v1, v2, sgn1);   // xor 2  (quad_perm [2,3,0,1])
        stage_shfl(v1, v2, sgn2, 4);     // xor 4  (ds_swizzle)
        stage_dpp<0x128>(v1, v2, sgn3);  // xor 8  (row_ror:8)
        stage_shfl(v1, v2, sgn4, 16);    // xor 16 (ds_swizzle)

        // scale by (1/sqrt2)^8 = 1/16; accumulate entropy partials; LDS scatter
        float c1[4] = {v1.x*0.0625f, v1.y*0.0625f, v1.z*0.0625f, v1.w*0.0625f};
        float c2[4] = {v2.x*0.0625f, v2.y*0.0625f, v2.z*0.0625f, v2.w*0.0625f};
        #pragma unroll
        for (int i = 0; i < 4; ++i) {
            const float s1 = c1[i] * c1[i];
            A1[i] += s1;
            B1[i] += s1 * __logf(s1 + 1e-35f); // c=0 -> term 0, matches p*log(p+eps)
            lds[kl][npos1[i]] = c1[i];
            const float s2 = c2[i] * c2[i];
            A2[i] += s2;
            B2[i] += s2 * __logf(s2 + 1e-35f);
            lds[kl][npos2[i]] = c2[i];
        }
    }
    __syncthreads();

    // Transposed, coalesced write: coeffs[b][m][k0 + kk .. kk+3]
    float* ob = coeffs + (size_t)b * T + k0;
    const int kk = (threadIdx.x & 3) * 4; // k offset within group (0,4,8,12)
    const int m0 = threadIdx.x >> 2;      // 0..63
    #pragma unroll
    for (int p = 0; p < 4; ++p) {
        const int m = p * 64 + m0;
        float4 v;
        v.x = lds[kk + 0][m];
        v.y = lds[kk + 1][m];
        v.z = lds[kk + 2][m];
        v.w = lds[kk + 3][m];
        *(float4*)(ob + (size_t)m * NCH + kk) = v;
    }
    __syncthreads();

    // Merge the two lane-halves (same node sets), then cross-wave reduce via LDS
    #pragma unroll
    for (int i = 0; i < 4; ++i) {
        A1[i] += __shfl_xor(A1[i], 32, 64); B1[i] += __shfl_xor(B1[i], 32, 64);
        A2[i] += __shfl_xor(A2[i], 32, 64); B2[i] += __shfl_xor(B2[i], 32, 64);
    }
    float* pl = &lds[0][0]; // need 4*512 = 2048 floats, have 16*257 = 4112
    if (half == 0) {
        #pragma unroll
        for (int i = 0; i < 4; ++i) {
            pl[wave * 512 + npos1[i]]       = A1[i];
            pl[wave * 512 + 256 + npos1[i]] = B1[i];
            pl[wave * 512 + npos2[i]]       = A2[i];
            pl[wave * 512 + 256 + npos2[i]] = B2[i];
        }
    }
    __syncthreads();

    const int n = threadIdx.x; // 0..255 = node
    const float A = pl[n] + pl[512 + n] + pl[1024 + n] + pl[1536 + n];
    const float B = pl[256 + n] + pl[768 + n] + pl[1280 + n] + pl[1792 + n];
    float* pp = part + (size_t)blockIdx.x * 512;
    pp[n]       = A;
    pp[256 + n] = B;
}

// finalize (R7 structure, unchanged): 512 blocks x 256 threads; block handles
// 64 rows; 16-group reduction split 4 groups/thread across 4 waves.
__global__ __launch_bounds__(256) void finalize_kernel(const float* __restrict__ part,
                                                       float* __restrict__ coeffs,
                                                       float* __restrict__ entropy,
                                                       float* __restrict__ keep) {
    __shared__ float pA[4][64], pB[4][64];

    const int gq   = threadIdx.x >> 6; // wave 0..3 -> groups gq*4 .. gq*4+3
    const int lane = threadIdx.x & 63;
    const int row0 = blockIdx.x * 64;  // 64 rows per block, all within one b
    const int row  = row0 + lane;      // this lane's (b, n)
    const int b    = row >> 8;
    const int n    = row & 255;

    float A = 0.f, B = 0.f;
    #pragma unroll
    for (int j = 0; j < 4; ++j) {
        const int g = gq * 4 + j;
        const float* p = part + (size_t)(b * NGRP + g) * 512;
        A += p[n];        // lanes: consecutive n -> coalesced 256B
        B += p[256 + n];
    }
    pA[gq][lane] = A;
    pB[gq][lane] = B;
    __syncthreads();

    if (threadIdx.x < 64) {
        A = pA[0][lane] + pA[1][lane] + pA[2][lane] + pA[3][lane];
        B = pB[0][lane] + pB[1][lane] + pB[2][lane] + pB[3][lane];

        const float S = A + 1e-8f;
        const float e = (A * __logf(S) - B) / S;
        const bool kp = e > 0.1f;

        entropy[row] = e;
        keep[row]    = kp ? 1.0f : 0.0f;

        // Rare path (never fires for Gaussian input): zero this node's coeff row.
        if (!kp) {
            float4 z = make_float4(0.f, 0.f, 0.f, 0.f);
            float4* cp = (float4*)(coeffs + (size_t)row * NCH);
            for (int j = 0; j < NCH / 4; ++j) cp[j] = z;
        }
    }
}

extern "C" void kernel_launch(void* const* d_in, const int* in_sizes, int n_in,
                              void* d_out, int out_size, void* d_ws, size_t ws_size,
                              hipStream_t stream) {
    const float* x = (const float*)d_in[0];

    float* coeffs  = (float*)d_out;                         // [128][256][256]
    float* entropy = coeffs + (size_t)BROWS * NODES * NCH;  // [128][256]
    float* keepf   = entropy + (size_t)BROWS * NODES;       // [128][256] as 0/1 float

    float* part = (float*)d_ws; // [2048 blocks][2][256] = 4 MB

    wht_kernel<<<dim3(BROWS * NGRP), dim3(256), 0, stream>>>(x, coeffs, part);
    // MEASUREMENT: finalize x3 (idempotent). (dur - 84.05)/2 = marginal cost.
    finalize_kernel<<<dim3(BROWS * NODES / 64), dim3(256), 0, stream>>>(part, coeffs, entropy, keepf);
    finalize_kernel<<<dim3(BROWS * NODES / 64), dim3(256), 0, stream>>>(part, coeffs, entropy, keepf);
    finalize_kernel<<<dim3(BROWS * NODES / 64), dim3(256), 0, stream>>>(part, coeffs, entropy, keepf);
}

// Round 14
// 84.498 us; speedup vs baseline: 1.0752x; 1.0363x over previous
//
#include <hip/hip_runtime.h>

// Problem constants (x: [128, 65536] fp32, LEVEL=8)
static constexpr int BROWS = 128;   // batch rows
static constexpr int T     = 65536; // samples per row
static constexpr int CL    = 256;   // chunk length = 2^LEVEL
static constexpr int NCH   = 256;   // chunks per row = T / CL (positions per node)
static constexpr int NODES = 256;   // 2^LEVEL leaves
static constexpr int KG    = 16;    // chunks handled per block (2048 blocks, 8/CU)
static constexpr int NGRP  = NCH / KG; // 16 chunk-groups per row
static constexpr int LSTR  = 257;   // padded LDS row stride (breaks bank conflicts)

// FINAL (R7 configuration, session best: 84.05 µs).
// Session ledger (all cross-checked):
//   42.0 µs  harness poison fill inside the timed window (not ours)
//   13.5 µs  wht kernel (R4-R2 marginal; ~11 µs BW roofline on 69 MB)
//    1.8 µs  finalize kernel (R13-R7 marginal /2)
//  ~28.5 µs  wht->finalize dispatch-transition cost — invariant to finalize
//            internals (R2/R7), NT stores/L2 residency (R9), part size (R0/R2);
//            all in-kernel alternatives measured worse: big-block fusion ~50 µs
//            (R3/R5/R6), atomics handoff ~49 µs (R11), per-thread fences 190 µs
//            (R1), cooperative launch rejected by validator (R10).

// Output row for Hadamard-order index h (in-place FWHT leaves Hadamard order):
//   c_nat[n] = H[bitrev8(n)], freq perm out[m] = c_nat[gray^-1(m)] => m = gray(bitrev8(h))
__device__ __forceinline__ int freq_pos(int h) {
    unsigned r = __brev((unsigned)h) >> 24; // bitrev8
    return (int)(r ^ (r >> 1));             // gray code
}

__device__ __forceinline__ void bfly01(float4& v) {
    // FWHT stages on j-bits 0,1 (within the float4)
    float4 w;
    w.x = v.x + v.y; w.y = v.x - v.y;
    w.z = v.z + v.w; w.w = v.z - v.w;
    v.x = w.x + w.z; v.z = w.x - w.z;
    v.y = w.y + w.w; v.w = w.y - w.w;
}

// Lane-exchange via DPP (VALU pipe — no LDS traffic). HW-validated.
// xor1 = quad_perm [1,0,3,2] = 0xB1; xor2 = quad_perm [2,3,0,1] = 0x4E;
// xor8 = row_ror:8 = 0x128 ((i+8)%16 == i^8 within a 16-lane row).
template<int CTRL>
__device__ __forceinline__ float xchg_dpp(float v) {
    return __builtin_bit_cast(float,
        __builtin_amdgcn_update_dpp(0, __builtin_bit_cast(int, v), CTRL, 0xF, 0xF, true));
}

template<int CTRL>
__device__ __forceinline__ void stage_dpp(float4& v1, float4& v2, float sgn) {
    float o;
    o = xchg_dpp<CTRL>(v1.x); v1.x = fmaf(sgn, v1.x, o);
    o = xchg_dpp<CTRL>(v1.y); v1.y = fmaf(sgn, v1.y, o);
    o = xchg_dpp<CTRL>(v1.z); v1.z = fmaf(sgn, v1.z, o);
    o = xchg_dpp<CTRL>(v1.w); v1.w = fmaf(sgn, v1.w, o);
    o = xchg_dpp<CTRL>(v2.x); v2.x = fmaf(sgn, v2.x, o);
    o = xchg_dpp<CTRL>(v2.y); v2.y = fmaf(sgn, v2.y, o);
    o = xchg_dpp<CTRL>(v2.z); v2.z = fmaf(sgn, v2.z, o);
    o = xchg_dpp<CTRL>(v2.w); v2.w = fmaf(sgn, v2.w, o);
}

__device__ __forceinline__ void stage_shfl(float4& v1, float4& v2, float sgn, int mask) {
    float o;
    o = __shfl_xor(v1.x, mask, 64); v1.x = fmaf(sgn, v1.x, o);
    o = __shfl_xor(v1.y, mask, 64); v1.y = fmaf(sgn, v1.y, o);
    o = __shfl_xor(v1.z, mask, 64); v1.z = fmaf(sgn, v1.z, o);
    o = __shfl_xor(v1.w, mask, 64); v1.w = fmaf(sgn, v1.w, o);
    o = __shfl_xor(v2.x, mask, 64); v2.x = fmaf(sgn, v2.x, o);
    o = __shfl_xor(v2.y, mask, 64); v2.y = fmaf(sgn, v2.y, o);
    o = __shfl_xor(v2.z, mask, 64); v2.z = fmaf(sgn, v2.z, o);
    o = __shfl_xor(v2.w, mask, 64); v2.w = fmaf(sgn, v2.w, o);
}

// Per block: 16 chunks of one batch row -> 256-pt FWHT (dual-chunk wave layout)
// -> freq-ordered transposed coeffs write + per-node entropy partials into ws.
__global__ __launch_bounds__(256) void wht_kernel(const float* __restrict__ x,
                                                  float* __restrict__ coeffs,
                                                  float* __restrict__ part) {
    __shared__ float lds[KG][LSTR]; // 16.5 KB; reused as 4x2x256 partial buffer later

    const int b    = blockIdx.x >> 4;  // 16 chunk-groups per row
    const int kg   = blockIdx.x & 15;
    const int k0   = kg * KG;
    const int lane = threadIdx.x & 63;
    const int wave = threadIdx.x >> 6; // 4 waves
    const int half = lane >> 5;        // which of 2 concurrent chunks
    const int L    = lane & 31;        // position within chunk (j-bits 2..6)

    const float* xb = x + (size_t)b * T;

    // lane owns the SAME 8 nodes (h = 4L+i and 128+4L+i) in every chunk
    int npos1[4], npos2[4];
    #pragma unroll
    for (int i = 0; i < 4; ++i) {
        npos1[i] = freq_pos(4 * L + i);
        npos2[i] = freq_pos(128 + 4 * L + i);
    }
    float A1[4] = {0.f,0.f,0.f,0.f}, B1[4] = {0.f,0.f,0.f,0.f};
    float A2[4] = {0.f,0.f,0.f,0.f}, B2[4] = {0.f,0.f,0.f,0.f};

    // Butterfly signs for the 5 cross-lane stages (loop-invariant)
    const float sgn0 = 1.0f - 2.0f * (float)((L >> 0) & 1);
    const float sgn1 = 1.0f - 2.0f * (float)((L >> 1) & 1);
    const float sgn2 = 1.0f - 2.0f * (float)((L >> 2) & 1);
    const float sgn3 = 1.0f - 2.0f * (float)((L >> 3) & 1);
    const float sgn4 = 1.0f - 2.0f * (float)((L >> 4) & 1);

    // Each wave handles 4 chunks as 2 iterations x 2 chunks (one per lane-half)
    #pragma unroll
    for (int it = 0; it < 2; ++it) {
        const int kl = wave * 4 + it * 2 + half; // local chunk row in LDS (0..15)
        const float* cp = xb + (size_t)(k0 + kl) * CL + 4 * L;
        float4 v1 = *(const float4*)(cp);        // j = 4L+i      (bit7=0)
        float4 v2 = *(const float4*)(cp + 128);  // j = 128+4L+i  (bit7=1)

        // FWHT stage j-bit7 (across the two registers, pure VALU)
        float4 t;
        t.x = v1.x - v2.x; t.y = v1.y - v2.y; t.z = v1.z - v2.z; t.w = v1.w - v2.w;
        v1.x += v2.x; v1.y += v2.y; v1.z += v2.z; v1.w += v2.w;
        v2 = t;

        // FWHT stages j-bits 0,1 (intra-float4)
        bfly01(v1);
        bfly01(v2);

        // FWHT stages j-bits 2..6 = lane xor 1,2,4,8,16.
        stage_dpp<0xB1>(v1, v2, sgn0);   // xor 1  (quad_perm [1,0,3,2])
        stage_dpp<0x4E>(v1, v2, sgn1);   // xor 2  (quad_perm [2,3,0,1])
        stage_shfl(v1, v2, sgn2, 4);     // xor 4  (ds_swizzle)
        stage_dpp<0x128>(v1, v2, sgn3);  // xor 8  (row_ror:8)
        stage_shfl(v1, v2, sgn4, 16);    // xor 16 (ds_swizzle)

        // scale by (1/sqrt2)^8 = 1/16; accumulate entropy partials; LDS scatter
        float c1[4] = {v1.x*0.0625f, v1.y*0.0625f, v1.z*0.0625f, v1.w*0.0625f};
        float c2[4] = {v2.x*0.0625f, v2.y*0.0625f, v2.z*0.0625f, v2.w*0.0625f};
        #pragma unroll
        for (int i = 0; i < 4; ++i) {
            const float s1 = c1[i] * c1[i];
            A1[i] += s1;
            B1[i] += s1 * __logf(s1 + 1e-35f); // c=0 -> term 0, matches p*log(p+eps)
            lds[kl][npos1[i]] = c1[i];
            const float s2 = c2[i] * c2[i];
            A2[i] += s2;
            B2[i] += s2 * __logf(s2 + 1e-35f);
            lds[kl][npos2[i]] = c2[i];
        }
    }
    __syncthreads();

    // Transposed, coalesced write: coeffs[b][m][k0 + kk .. kk+3]
    float* ob = coeffs + (size_t)b * T + k0;
    const int kk = (threadIdx.x & 3) * 4; // k offset within group (0,4,8,12)
    const int m0 = threadIdx.x >> 2;      // 0..63
    #pragma unroll
    for (int p = 0; p < 4; ++p) {
        const int m = p * 64 + m0;
        float4 v;
        v.x = lds[kk + 0][m];
        v.y = lds[kk + 1][m];
        v.z = lds[kk + 2][m];
        v.w = lds[kk + 3][m];
        *(float4*)(ob + (size_t)m * NCH + kk) = v;
    }
    __syncthreads();

    // Merge the two lane-halves (same node sets), then cross-wave reduce via LDS
    #pragma unroll
    for (int i = 0; i < 4; ++i) {
        A1[i] += __shfl_xor(A1[i], 32, 64); B1[i] += __shfl_xor(B1[i], 32, 64);
        A2[i] += __shfl_xor(A2[i], 32, 64); B2[i] += __shfl_xor(B2[i], 32, 64);
    }
    float* pl = &lds[0][0]; // need 4*512 = 2048 floats, have 16*257 = 4112
    if (half == 0) {
        #pragma unroll
        for (int i = 0; i < 4; ++i) {
            pl[wave * 512 + npos1[i]]       = A1[i];
            pl[wave * 512 + 256 + npos1[i]] = B1[i];
            pl[wave * 512 + npos2[i]]       = A2[i];
            pl[wave * 512 + 256 + npos2[i]] = B2[i];
        }
    }
    __syncthreads();

    const int n = threadIdx.x; // 0..255 = node
    const float A = pl[n] + pl[512 + n] + pl[1024 + n] + pl[1536 + n];
    const float B = pl[256 + n] + pl[768 + n] + pl[1280 + n] + pl[1792 + n];
    float* pp = part + (size_t)blockIdx.x * 512;
    pp[n]       = A;
    pp[256 + n] = B;
}

// finalize: 512 blocks x 256 threads; block handles 64 rows; 16-group reduction
// split 4 groups/thread across 4 waves; LDS tree; wave 0 epilogue. 1.8 µs
// measured (R13). The ~28.5 µs observed on this dispatch edge is transition
// cost, invariant to this kernel's structure.
__global__ __launch_bounds__(256) void finalize_kernel(const float* __restrict__ part,
                                                       float* __restrict__ coeffs,
                                                       float* __restrict__ entropy,
                                                       float* __restrict__ keep) {
    __shared__ float pA[4][64], pB[4][64];

    const int gq   = threadIdx.x >> 6; // wave 0..3 -> groups gq*4 .. gq*4+3
    const int lane = threadIdx.x & 63;
    const int row0 = blockIdx.x * 64;  // 64 rows per block, all within one b
    const int row  = row0 + lane;      // this lane's (b, n)
    const int b    = row >> 8;
    const int n    = row & 255;

    float A = 0.f, B = 0.f;
    #pragma unroll
    for (int j = 0; j < 4; ++j) {
        const int g = gq * 4 + j;
        const float* p = part + (size_t)(b * NGRP + g) * 512;
        A += p[n];        // lanes: consecutive n -> coalesced 256B
        B += p[256 + n];
    }
    pA[gq][lane] = A;
    pB[gq][lane] = B;
    __syncthreads();

    if (threadIdx.x < 64) {
        A = pA[0][lane] + pA[1][lane] + pA[2][lane] + pA[3][lane];
        B = pB[0][lane] + pB[1][lane] + pB[2][lane] + pB[3][lane];

        const float S = A + 1e-8f;
        const float e = (A * __logf(S) - B) / S;
        const bool kp = e > 0.1f;

        entropy[row] = e;
        keep[row]    = kp ? 1.0f : 0.0f;

        // Rare path (never fires for Gaussian input): zero this node's coeff row.
        if (!kp) {
            float4 z = make_float4(0.f, 0.f, 0.f, 0.f);
            float4* cp = (float4*)(coeffs + (size_t)row * NCH);
            for (int j = 0; j < NCH / 4; ++j) cp[j] = z;
        }
    }
}

extern "C" void kernel_launch(void* const* d_in, const int* in_sizes, int n_in,
                              void* d_out, int out_size, void* d_ws, size_t ws_size,
                              hipStream_t stream) {
    const float* x = (const float*)d_in[0];

    float* coeffs  = (float*)d_out;                         // [128][256][256]
    float* entropy = coeffs + (size_t)BROWS * NODES * NCH;  // [128][256]
    float* keepf   = entropy + (size_t)BROWS * NODES;       // [128][256] as 0/1 float

    float* part = (float*)d_ws; // [2048 blocks][2][256] = 4 MB

    wht_kernel<<<dim3(BROWS * NGRP), dim3(256), 0, stream>>>(x, coeffs, part);
    finalize_kernel<<<dim3(BROWS * NODES / 64), dim3(256), 0, stream>>>(part, coeffs, entropy, keepf);
}